// Round 1
// baseline (709.590 us; speedup 1.0000x reference)
//
#include <hip/hip_runtime.h>

// ---------------- constants ----------------
#define BB 2
#define SEQ 4096
#define LQ 4064
#define HID 1024
#define NH 16
#define HD 64
#define NB 64      // number of 64-wide blocks in sequence
#define BLK 64
#define NR 3
#define PENV -10000.0f

typedef __bf16 bf16;
typedef __bf16 bf16x8 __attribute__((ext_vector_type(8)));
typedef float floatx4 __attribute__((ext_vector_type(4)));

__device__ inline floatx4 mfma16(bf16x8 a, bf16x8 b, floatx4 c) {
    return __builtin_amdgcn_mfma_f32_16x16x32_bf16(a, b, c, 0, 0, 0);
}

// ---------------- prep: pad + cast X to bf16 ----------------
// Xp layout: [B*SEQ][HID] bf16, rows s>=LQ zeroed
__global__ __launch_bounds__(256) void cast_pad_x(const float* __restrict__ X,
                                                  bf16* __restrict__ Xp) {
    int t = blockIdx.x * 256 + threadIdx.x;   // 8192*256 threads
    int c4 = t & 255;                         // column group (4 floats)
    int row = t >> 8;                         // 0..8191
    int b = row >> 12;
    int s = row & 4095;
    float4 v = make_float4(0.f, 0.f, 0.f, 0.f);
    if (s < LQ) {
        v = reinterpret_cast<const float4*>(X + ((size_t)(b * LQ + s)) * HID)[c4];
    }
    union { bf16 h[4]; uint2 u; } o;
    o.h[0] = (bf16)v.x; o.h[1] = (bf16)v.y; o.h[2] = (bf16)v.z; o.h[3] = (bf16)v.w;
    *reinterpret_cast<uint2*>(Xp + (size_t)row * HID + c4 * 4) = o.u;
}

// ---------------- prep: transpose + cast weights ----------------
// dst[j][k] = src[k][j]  (N-major "B^T" form for the gemm_bt structure)
__global__ __launch_bounds__(256) void transpose_w(const float* __restrict__ Wq,
                                                   const float* __restrict__ Wk,
                                                   const float* __restrict__ Wv,
                                                   const float* __restrict__ Wo,
                                                   bf16* __restrict__ WqkvT,
                                                   bf16* __restrict__ WoT) {
    __shared__ float tile[64][65];
    int sel = blockIdx.z;
    const float* src = (sel == 0) ? Wq : (sel == 1) ? Wk : (sel == 2) ? Wv : Wo;
    bf16* dst = (sel < 3) ? (WqkvT + (size_t)sel * HID * HID) : WoT;
    int j0 = blockIdx.x * 64, k0 = blockIdx.y * 64;
    int tx = threadIdx.x, ty = threadIdx.y;   // (64,4)
    for (int i = 0; i < 16; i++) {
        int k = ty + i * 4;
        tile[k][tx] = src[(size_t)(k0 + k) * HID + j0 + tx];
    }
    __syncthreads();
    for (int i = 0; i < 16; i++) {
        int j = ty + i * 4;
        dst[(size_t)(j0 + j) * HID + k0 + tx] = (bf16)tile[tx][j];
    }
}

// ---------------- GEMM1: QKV projection ----------------
// C[8192][3072] = Xp[8192][1024] * WqkvT[3072][1024]^T, scatter to q/k/v (B,H,S,D) bf16
__global__ __launch_bounds__(256) void gemm_qkv(const bf16* __restrict__ Xp,
                                                const bf16* __restrict__ WT,
                                                const float* __restrict__ bq,
                                                const float* __restrict__ bk,
                                                const float* __restrict__ bv,
                                                bf16* __restrict__ qo,
                                                bf16* __restrict__ ko,
                                                bf16* __restrict__ vo) {
    __shared__ __align__(16) bf16 As[128 * 64];
    __shared__ __align__(16) bf16 Bs[128 * 64];
    int tid = threadIdx.x;
    int wave = tid >> 6, lane = tid & 63;
    int quad = lane >> 4, lm = lane & 15;
    int tile_m = blockIdx.x * 128;
    int tile_n = blockIdx.y * 128;
    int wm = (wave & 1) * 64, wn = (wave >> 1) * 64;

    floatx4 acc[4][4] = {};

    for (int k0 = 0; k0 < HID; k0 += 64) {
        __syncthreads();
        for (int it = 0; it < 4; it++) {
            int c = it * 256 + tid;           // 0..1023
            int row = c >> 3, col = (c & 7) * 8;
            *reinterpret_cast<uint4*>(&As[row * 64 + col]) =
                *reinterpret_cast<const uint4*>(Xp + (size_t)(tile_m + row) * HID + k0 + col);
            *reinterpret_cast<uint4*>(&Bs[row * 64 + col]) =
                *reinterpret_cast<const uint4*>(WT + (size_t)(tile_n + row) * HID + k0 + col);
        }
        __syncthreads();
        for (int ks = 0; ks < 64; ks += 32) {
            bf16x8 a[4], b[4];
            for (int i = 0; i < 4; i++)
                a[i] = *reinterpret_cast<const bf16x8*>(&As[(wm + i * 16 + lm) * 64 + ks + quad * 8]);
            for (int j = 0; j < 4; j++)
                b[j] = *reinterpret_cast<const bf16x8*>(&Bs[(wn + j * 16 + lm) * 64 + ks + quad * 8]);
            for (int i = 0; i < 4; i++)
                for (int j = 0; j < 4; j++)
                    acc[i][j] = mfma16(a[i], b[j], acc[i][j]);
        }
    }

    for (int i = 0; i < 4; i++) {
        for (int j = 0; j < 4; j++) {
            int nn = tile_n + wn + j * 16 + lm;
            int which = nn >> 10;             // 0=q,1=k,2=v
            int hc = nn & 1023;
            const float* bias = (which == 0) ? bq : (which == 1) ? bk : bv;
            bf16* dstb = (which == 0) ? qo : (which == 1) ? ko : vo;
            float bsv = bias[hc];
            int h = hc >> 6, d = hc & 63;
            for (int r = 0; r < 4; r++) {
                int mm = tile_m + wm + i * 16 + quad * 4 + r;
                int b_ = mm >> 12, s = mm & 4095;
                float val = acc[i][j][r] + bsv;
                if (which == 0) val *= 0.125f;   // pre-scale q by 1/sqrt(D), exact in bf16
                dstb[((size_t)((b_ * NH + h) * SEQ + s)) * HD + d] = (bf16)val;
            }
        }
    }
}

// ---------------- attention ----------------
// grid: (64, B*NH). blockIdx.x permuted so full rows (l=0,63) dispatch first.
__global__ __launch_bounds__(256) void attn_kernel(const bf16* __restrict__ q,
                                                   const bf16* __restrict__ kk,
                                                   const bf16* __restrict__ vv,
                                                   const float* __restrict__ band,
                                                   const float* __restrict__ fromm,
                                                   const float* __restrict__ tom,
                                                   const float* __restrict__ blocked,
                                                   const int* __restrict__ rand_attn,
                                                   bf16* __restrict__ attn) {
    __shared__ __align__(16) bf16 Ks[64 * 64];
    __shared__ __align__(16) bf16 VT[64 * 72];
    __shared__ __align__(16) bf16 Ps[4][16 * 72];

    int tid = threadIdx.x, wave = tid >> 6, lane = tid & 63;
    int quad = lane >> 4, lm = lane & 15;
    int idx = blockIdx.x;
    int l = (idx == 0) ? 0 : ((idx == 1) ? (NB - 1) : idx - 1);
    int bh = blockIdx.y;
    int b = bh >> 4, h = bh & 15;
    size_t bh_base = (size_t)bh * SEQ * HD;

    // Q fragments (A-operand layout: m=lane&15, k=quad*8+j), kept in registers
    int qrow_m = wave * 16 + lm;  // query row within block for A-frag
    bf16x8 aq[2];
    for (int kt = 0; kt < 2; kt++)
        aq[kt] = *reinterpret_cast<const bf16x8*>(
            q + bh_base + (size_t)(l * BLK + qrow_m) * HD + kt * 32 + quad * 8);

    floatx4 ctx[4] = {};
    float mrun[4], lrun[4], mqv[4];
    for (int r = 0; r < 4; r++) { mrun[r] = -1e30f; lrun[r] = 0.f; }
    for (int r = 0; r < 4; r++)
        mqv[r] = blocked[((size_t)b * NB + l) * BLK + wave * 16 + quad * 4 + r];

    // key block list. type: 0=to_mask, 1..3=band(t), 4=rand
    bool full = (l == 0 || l == NB - 1);
    int blist[8], btype[8];
    int nblocks;
    if (full) {
        nblocks = NB;
    } else {
        int base;
        if (l == 1) {
            blist[0] = 0; blist[1] = 1; blist[2] = 2; blist[3] = NB - 1;
            btype[0] = btype[1] = btype[2] = btype[3] = 0;
            base = 4;
        } else if (l == NB - 2) {
            blist[0] = 0; blist[1] = NB - 3; blist[2] = NB - 2; blist[3] = NB - 1;
            btype[0] = btype[1] = btype[2] = btype[3] = 0;
            base = 4;
        } else {
            blist[0] = 0;      btype[0] = 0;
            blist[1] = l - 1;  btype[1] = 1;
            blist[2] = l;      btype[2] = 2;
            blist[3] = l + 1;  btype[3] = 3;
            blist[4] = NB - 1; btype[4] = 0;
            base = 5;
        }
        const int* ra = rand_attn + ((size_t)(b * NH + h) * (NB - 2) + (l - 1)) * NR;
        for (int r = 0; r < NR; r++) { blist[base + r] = ra[r]; btype[base + r] = 4; }
        nblocks = base + NR;
    }

    for (int kbi = 0; kbi < nblocks; kbi++) {
        int kb  = full ? kbi : blist[kbi];
        int typ = full ? 0   : btype[kbi];

        __syncthreads();   // protect Ks/VT from previous iteration's readers
        // stage K (row-major [key][d]) and V transposed ([d][key], stride 72)
        for (int it = 0; it < 2; it++) {
            int c = it * 256 + tid;           // 0..511
            int krow = c >> 3, col = (c & 7) * 8;
            *reinterpret_cast<uint4*>(&Ks[krow * 64 + col]) =
                *reinterpret_cast<const uint4*>(kk + bh_base + (size_t)(kb * BLK + krow) * HD + col);
            union { uint4 u; bf16 hh[8]; } v8;
            v8.u = *reinterpret_cast<const uint4*>(vv + bh_base + (size_t)(kb * BLK + krow) * HD + col);
            for (int jj = 0; jj < 8; jj++)
                VT[(col + jj) * 72 + krow] = v8.hh[jj];
        }
        __syncthreads();

        // S = Q K^T  (q pre-scaled by 1/sqrt(D))
        floatx4 sc[4];
        for (int f = 0; f < 4; f++) {
            bf16x8 b0 = *reinterpret_cast<const bf16x8*>(&Ks[(f * 16 + lm) * 64 + quad * 8]);
            bf16x8 b1 = *reinterpret_cast<const bf16x8*>(&Ks[(f * 16 + lm) * 64 + 32 + quad * 8]);
            floatx4 z = {0.f, 0.f, 0.f, 0.f};
            z = mfma16(aq[0], b0, z);
            z = mfma16(aq[1], b1, z);
            sc[f] = z;
        }

        // masks / penalties
        for (int f = 0; f < 4; f++) {
            int keyl = f * 16 + lm;
            if (typ == 0) {
                float tm = tom[(size_t)b * SEQ + kb * BLK + keyl];
                float pen = (1.f - tm) * PENV;
                for (int r = 0; r < 4; r++) sc[f][r] += pen;
            } else if (typ == 4) {
                float mk = blocked[((size_t)b * NB + kb) * BLK + keyl];
                for (int r = 0; r < 4; r++) sc[f][r] += (1.f - mqv[r] * mk) * PENV;
            } else {
                int t = typ - 1;
                const float* bp = band + (((size_t)b * (NB - 4) + (l - 2)) * BLK) * 192;
                for (int r = 0; r < 4; r++) {
                    float bm = bp[(size_t)(wave * 16 + quad * 4 + r) * 192 + t * 64 + keyl];
                    sc[f][r] += (1.f - bm) * PENV;
                }
            }
        }

        // online softmax (rows = quad*4+r within this wave's 16 queries)
        for (int r = 0; r < 4; r++) {
            float mx = fmaxf(fmaxf(sc[0][r], sc[1][r]), fmaxf(sc[2][r], sc[3][r]));
            for (int off = 1; off < 16; off <<= 1)
                mx = fmaxf(mx, __shfl_xor(mx, off, 64));
            float mnew = fmaxf(mrun[r], mx);
            float scale = __expf(mrun[r] - mnew);
            float rs = 0.f;
            for (int f = 0; f < 4; f++) {
                float p = __expf(sc[f][r] - mnew);
                sc[f][r] = p;
                rs += p;
            }
            for (int off = 1; off < 16; off <<= 1)
                rs += __shfl_xor(rs, off, 64);
            lrun[r] = lrun[r] * scale + rs;
            mrun[r] = mnew;
            for (int j = 0; j < 4; j++) ctx[j] [r] *= scale;
        }

        // P: C-layout -> LDS -> A-layout (per-wave private region, in-order LDS)
        for (int f = 0; f < 4; f++)
            for (int r = 0; r < 4; r++)
                Ps[wave][(quad * 4 + r) * 72 + f * 16 + lm] = (bf16)sc[f][r];

        bf16x8 ap0 = *reinterpret_cast<const bf16x8*>(&Ps[wave][lm * 72 + quad * 8]);
        bf16x8 ap1 = *reinterpret_cast<const bf16x8*>(&Ps[wave][lm * 72 + 32 + quad * 8]);
        for (int j = 0; j < 4; j++) {
            bf16x8 bv0 = *reinterpret_cast<const bf16x8*>(&VT[(j * 16 + lm) * 72 + quad * 8]);
            bf16x8 bv1 = *reinterpret_cast<const bf16x8*>(&VT[(j * 16 + lm) * 72 + 32 + quad * 8]);
            ctx[j] = mfma16(ap0, bv0, ctx[j]);
            ctx[j] = mfma16(ap1, bv1, ctx[j]);
        }
    }

    // finalize: /l, *from_mask, store bf16 to attn[(b,s),(h,d)]
    for (int r = 0; r < 4; r++) {
        int qr = wave * 16 + quad * 4 + r;
        int sq = l * BLK + qr;
        float fm = fromm[(size_t)b * SEQ + sq];
        float inv = 1.f / lrun[r];
        for (int j = 0; j < 4; j++) {
            float val = ctx[j][r] * inv * fm;
            attn[((size_t)(b * SEQ + sq)) * HID + h * HD + j * 16 + lm] = (bf16)val;
        }
    }
}

// ---------------- GEMM2: output projection ----------------
__global__ __launch_bounds__(256) void gemm_out(const bf16* __restrict__ A,
                                                const bf16* __restrict__ WoT,
                                                const float* __restrict__ bo,
                                                float* __restrict__ out) {
    __shared__ __align__(16) bf16 As[128 * 64];
    __shared__ __align__(16) bf16 Bs[128 * 64];
    int tid = threadIdx.x;
    int wave = tid >> 6, lane = tid & 63;
    int quad = lane >> 4, lm = lane & 15;
    int tile_m = blockIdx.x * 128;
    int tile_n = blockIdx.y * 128;
    int wm = (wave & 1) * 64, wn = (wave >> 1) * 64;

    floatx4 acc[4][4] = {};

    for (int k0 = 0; k0 < HID; k0 += 64) {
        __syncthreads();
        for (int it = 0; it < 4; it++) {
            int c = it * 256 + tid;
            int row = c >> 3, col = (c & 7) * 8;
            *reinterpret_cast<uint4*>(&As[row * 64 + col]) =
                *reinterpret_cast<const uint4*>(A + (size_t)(tile_m + row) * HID + k0 + col);
            *reinterpret_cast<uint4*>(&Bs[row * 64 + col]) =
                *reinterpret_cast<const uint4*>(WoT + (size_t)(tile_n + row) * HID + k0 + col);
        }
        __syncthreads();
        for (int ks = 0; ks < 64; ks += 32) {
            bf16x8 a[4], b[4];
            for (int i = 0; i < 4; i++)
                a[i] = *reinterpret_cast<const bf16x8*>(&As[(wm + i * 16 + lm) * 64 + ks + quad * 8]);
            for (int j = 0; j < 4; j++)
                b[j] = *reinterpret_cast<const bf16x8*>(&Bs[(wn + j * 16 + lm) * 64 + ks + quad * 8]);
            for (int i = 0; i < 4; i++)
                for (int j = 0; j < 4; j++)
                    acc[i][j] = mfma16(a[i], b[j], acc[i][j]);
        }
    }

    for (int i = 0; i < 4; i++) {
        for (int j = 0; j < 4; j++) {
            int nn = tile_n + wn + j * 16 + lm;
            float bsv = bo[nn];
            for (int r = 0; r < 4; r++) {
                int mm = tile_m + wm + i * 16 + quad * 4 + r;
                int b_ = mm >> 12, s = mm & 4095;
                if (s < LQ)
                    out[((size_t)(b_ * LQ + s)) * HID + nn] = acc[i][j][r] + bsv;
            }
        }
    }
}

// ---------------- launcher ----------------
extern "C" void kernel_launch(void* const* d_in, const int* in_sizes, int n_in,
                              void* d_out, int out_size, void* d_ws, size_t ws_size,
                              hipStream_t stream) {
    const float* X       = (const float*)d_in[0];
    const float* Wq      = (const float*)d_in[1];
    const float* bq      = (const float*)d_in[2];
    const float* Wk      = (const float*)d_in[3];
    const float* bk      = (const float*)d_in[4];
    const float* Wv      = (const float*)d_in[5];
    const float* bv      = (const float*)d_in[6];
    const float* Wo      = (const float*)d_in[7];
    const float* bo      = (const float*)d_in[8];
    const float* band    = (const float*)d_in[9];
    const float* fromm   = (const float*)d_in[10];
    const float* tom     = (const float*)d_in[11];
    const float* blocked = (const float*)d_in[12];
    const int*   randa   = (const int*)d_in[13];
    float* out = (float*)d_out;

    char* ws = (char*)d_ws;
    bf16* Xp    = (bf16*)(ws + 0);              // 16,777,216 B (reused as attn)
    bf16* WqkvT = (bf16*)(ws + 16777216);       //  6,291,456 B
    bf16* WoT   = (bf16*)(ws + 23068672);       //  2,097,152 B
    bf16* qb    = (bf16*)(ws + 25165824);       // 16,777,216 B
    bf16* kb    = (bf16*)(ws + 41943040);       // 16,777,216 B
    bf16* vb    = (bf16*)(ws + 58720256);       // 16,777,216 B  (end 75,497,472)
    bf16* attnb = Xp;                           // Xp dead after gemm_qkv

    cast_pad_x<<<dim3(8192), dim3(256), 0, stream>>>(X, Xp);
    transpose_w<<<dim3(16, 16, 4), dim3(64, 4), 0, stream>>>(Wq, Wk, Wv, Wo, WqkvT, WoT);
    gemm_qkv<<<dim3(64, 24), dim3(256), 0, stream>>>(Xp, WqkvT, bq, bk, bv, qb, kb, vb);
    attn_kernel<<<dim3(64, BB * NH), dim3(256), 0, stream>>>(qb, kb, vb, band, fromm, tom,
                                                             blocked, randa, attnb);
    gemm_out<<<dim3(64, 8), dim3(256), 0, stream>>>(attnb, WoT, bo, out);
}

// Round 2
// 481.461 us; speedup vs baseline: 1.4738x; 1.4738x over previous
//
#include <hip/hip_runtime.h>

// ---------------- constants ----------------
#define BB 2
#define SEQ 4096
#define LQ 4064
#define HID 1024
#define NH 16
#define HD 64
#define NB 64      // number of 64-wide blocks in sequence
#define BLK 64
#define NR 3
#define PENV -10000.0f

typedef __bf16 bf16;
typedef __bf16 bf16x8 __attribute__((ext_vector_type(8)));
typedef float floatx4 __attribute__((ext_vector_type(4)));

__device__ inline floatx4 mfma16(bf16x8 a, bf16x8 b, floatx4 c) {
    return __builtin_amdgcn_mfma_f32_16x16x32_bf16(a, b, c, 0, 0, 0);
}

// async global->LDS, 16B per lane (global_load_lds_dwordx4)
__device__ inline void async_ld16(const bf16* g, bf16* l) {
    __builtin_amdgcn_global_load_lds(
        (const __attribute__((address_space(1))) unsigned int*)g,
        (__attribute__((address_space(3))) unsigned int*)l, 16, 0, 0);
}

// ---------------- prep: pad + cast X to bf16 ----------------
__global__ __launch_bounds__(256) void cast_pad_x(const float* __restrict__ X,
                                                  bf16* __restrict__ Xp) {
    int t = blockIdx.x * 256 + threadIdx.x;
    int c4 = t & 255;
    int row = t >> 8;
    int b = row >> 12;
    int s = row & 4095;
    float4 v = make_float4(0.f, 0.f, 0.f, 0.f);
    if (s < LQ) {
        v = reinterpret_cast<const float4*>(X + ((size_t)(b * LQ + s)) * HID)[c4];
    }
    union { bf16 h[4]; uint2 u; } o;
    o.h[0] = (bf16)v.x; o.h[1] = (bf16)v.y; o.h[2] = (bf16)v.z; o.h[3] = (bf16)v.w;
    *reinterpret_cast<uint2*>(Xp + (size_t)row * HID + c4 * 4) = o.u;
}

// ---------------- prep: transpose + cast weights ----------------
__global__ __launch_bounds__(256) void transpose_w(const float* __restrict__ Wq,
                                                   const float* __restrict__ Wk,
                                                   const float* __restrict__ Wv,
                                                   const float* __restrict__ Wo,
                                                   bf16* __restrict__ WqkvT,
                                                   bf16* __restrict__ WoT) {
    __shared__ float tile[64][65];
    int sel = blockIdx.z;
    const float* src = (sel == 0) ? Wq : (sel == 1) ? Wk : (sel == 2) ? Wv : Wo;
    bf16* dst = (sel < 3) ? (WqkvT + (size_t)sel * HID * HID) : WoT;
    int j0 = blockIdx.x * 64, k0 = blockIdx.y * 64;
    int tx = threadIdx.x, ty = threadIdx.y;   // (64,4)
    for (int i = 0; i < 16; i++) {
        int k = ty + i * 4;
        tile[k][tx] = src[(size_t)(k0 + k) * HID + j0 + tx];
    }
    __syncthreads();
    for (int i = 0; i < 16; i++) {
        int j = ty + i * 4;
        dst[(size_t)(j0 + j) * HID + k0 + tx] = (bf16)tile[tx][j];
    }
}

// ---------------- GEMM1: QKV projection ----------------
// q,k stored (b,h,s,d); v stored TRANSPOSED (b,h,d,s) for direct PV B-frag loads
__global__ __launch_bounds__(256) void gemm_qkv(const bf16* __restrict__ Xp,
                                                const bf16* __restrict__ WT,
                                                const float* __restrict__ bq,
                                                const float* __restrict__ bk,
                                                const float* __restrict__ bv,
                                                bf16* __restrict__ qo,
                                                bf16* __restrict__ ko,
                                                bf16* __restrict__ vt) {
    __shared__ __align__(16) bf16 As[128 * 64];
    __shared__ __align__(16) bf16 Bs[128 * 64];
    int tid = threadIdx.x;
    int wave = tid >> 6, lane = tid & 63;
    int quad = lane >> 4, lm = lane & 15;
    int tile_m = blockIdx.x * 128;
    int tile_n = blockIdx.y * 128;
    int wm = (wave & 1) * 64, wn = (wave >> 1) * 64;

    floatx4 acc[4][4] = {};

    for (int k0 = 0; k0 < HID; k0 += 64) {
        __syncthreads();
        for (int it = 0; it < 4; it++) {
            int c = it * 256 + tid;           // 0..1023; LDS offset = c*16B (lane-contig)
            int row = c >> 3, col = (c & 7) * 8;
            async_ld16(Xp + (size_t)(tile_m + row) * HID + k0 + col, &As[c * 8]);
            async_ld16(WT + (size_t)(tile_n + row) * HID + k0 + col, &Bs[c * 8]);
        }
        __syncthreads();
        for (int ks = 0; ks < 64; ks += 32) {
            bf16x8 a[4], b[4];
            for (int i = 0; i < 4; i++)
                a[i] = *reinterpret_cast<const bf16x8*>(&As[(wm + i * 16 + lm) * 64 + ks + quad * 8]);
            for (int j = 0; j < 4; j++)
                b[j] = *reinterpret_cast<const bf16x8*>(&Bs[(wn + j * 16 + lm) * 64 + ks + quad * 8]);
            for (int i = 0; i < 4; i++)
                for (int j = 0; j < 4; j++)
                    acc[i][j] = mfma16(a[i], b[j], acc[i][j]);
        }
    }

    for (int i = 0; i < 4; i++) {
        for (int j = 0; j < 4; j++) {
            int nn = tile_n + wn + j * 16 + lm;
            int which = nn >> 10;             // 0=q,1=k,2=v
            int hc = nn & 1023;
            const float* bias = (which == 0) ? bq : (which == 1) ? bk : bv;
            float bsv = bias[hc];
            int h = hc >> 6, d = hc & 63;
            for (int r = 0; r < 4; r++) {
                int mm = tile_m + wm + i * 16 + quad * 4 + r;
                int b_ = mm >> 12, s = mm & 4095;
                float val = acc[i][j][r] + bsv;
                if (which == 0) {
                    qo[((size_t)((b_ * NH + h) * SEQ + s)) * HD + d] = (bf16)(val * 0.125f);
                } else if (which == 1) {
                    ko[((size_t)((b_ * NH + h) * SEQ + s)) * HD + d] = (bf16)val;
                } else {
                    vt[((size_t)((b_ * NH + h) * HD + d)) * SEQ + s] = (bf16)val;
                }
            }
        }
    }
}

// ---------------- attention ----------------
// grid: (70, B*NH). x<8: full rows (l=0 / 63), sub=x&3, 4 waves split 64 K-blocks,
//                   LDS online-softmax combine at the end.
// x>=8: middle row l=x-7, each wave = one 16-query subtile, fully independent
//                   (no barriers, no K/V staging — direct-from-global MFMA frags).
__global__ __launch_bounds__(256) void attn_kernel(const bf16* __restrict__ q,
                                                   const bf16* __restrict__ kk,
                                                   const bf16* __restrict__ vt,
                                                   const float* __restrict__ band,
                                                   const float* __restrict__ fromm,
                                                   const float* __restrict__ tom,
                                                   const float* __restrict__ blocked,
                                                   const int* __restrict__ rand_attn,
                                                   bf16* __restrict__ attn) {
    // loop phase: per-wave P-transpose regions (16x72 bf16 = 2304 B each)
    // full-row epilogue (after barrier): ctx[4][16][64] f32 (16 KB) + m/l [4][16] each
    __shared__ __align__(16) char smem[4 * 16 * 64 * 4 + 2 * 4 * 16 * 4];

    int tid = threadIdx.x, wave = tid >> 6, lane = tid & 63;
    int quad = lane >> 4, lm = lane & 15;
    int bh = blockIdx.y;
    int b = bh >> 4, h = bh & 15;
    size_t bh_base = (size_t)bh * SEQ * HD;
    int x = blockIdx.x;
    bool fullmode = (x < 8);
    int l, sub;
    if (fullmode) { l = (x >> 2) ? (NB - 1) : 0; sub = x & 3; }
    else          { l = x - 7;                   sub = wave;  }

    // Q fragments (A-layout: m=lm, k=quad*8+j), q pre-scaled by 1/sqrt(D)
    bf16x8 aq[2];
    for (int kt = 0; kt < 2; kt++)
        aq[kt] = *reinterpret_cast<const bf16x8*>(
            q + bh_base + (size_t)(l * BLK + sub * 16 + lm) * HD + kt * 32 + quad * 8);

    floatx4 ctx[4] = {};
    float mrun[4], lrun[4], mqv[4];
    for (int r = 0; r < 4; r++) { mrun[r] = -1e30f; lrun[r] = 0.f; }
    for (int r = 0; r < 4; r++)
        mqv[r] = blocked[((size_t)b * NB + l) * BLK + sub * 16 + quad * 4 + r];

    // key-block list (middle mode). type: 0=to_mask, 1..3=band(t), 4=rand
    int blist[8], btype[8];
    int nblocks;
    if (fullmode) {
        nblocks = 16;    // this wave's chunk: kb = wave*16 + it
    } else {
        int base;
        if (l == 1) {
            blist[0] = 0; blist[1] = 1; blist[2] = 2; blist[3] = NB - 1;
            btype[0] = btype[1] = btype[2] = btype[3] = 0;
            base = 4;
        } else if (l == NB - 2) {
            blist[0] = 0; blist[1] = NB - 3; blist[2] = NB - 2; blist[3] = NB - 1;
            btype[0] = btype[1] = btype[2] = btype[3] = 0;
            base = 4;
        } else {
            blist[0] = 0;      btype[0] = 0;
            blist[1] = l - 1;  btype[1] = 1;
            blist[2] = l;      btype[2] = 2;
            blist[3] = l + 1;  btype[3] = 3;
            blist[4] = NB - 1; btype[4] = 0;
            base = 5;
        }
        const int* ra = rand_attn + ((size_t)(b * NH + h) * (NB - 2) + (l - 1)) * NR;
        for (int r = 0; r < NR; r++) { blist[base + r] = ra[r]; btype[base + r] = 4; }
        nblocks = base + NR;
    }

    bf16* pw = (bf16*)smem + wave * 16 * 72;

    for (int it = 0; it < nblocks; it++) {
        int kb  = fullmode ? (wave * 16 + it) : blist[it];
        int typ = fullmode ? 0 : btype[it];

        // S = Q K^T : B-frags direct from global (K row-major)
        const bf16* kbase = kk + bh_base + (size_t)kb * BLK * HD;
        floatx4 sc[4];
        for (int f = 0; f < 4; f++) {
            bf16x8 b0 = *reinterpret_cast<const bf16x8*>(kbase + (f * 16 + lm) * HD + quad * 8);
            bf16x8 b1 = *reinterpret_cast<const bf16x8*>(kbase + (f * 16 + lm) * HD + 32 + quad * 8);
            floatx4 z = {0.f, 0.f, 0.f, 0.f};
            z = mfma16(aq[0], b0, z);
            z = mfma16(aq[1], b1, z);
            sc[f] = z;
        }

        // masks / penalties
        for (int f = 0; f < 4; f++) {
            int keyl = f * 16 + lm;
            if (typ == 0) {
                float tm = tom[(size_t)b * SEQ + kb * BLK + keyl];
                float pen = (1.f - tm) * PENV;
                for (int r = 0; r < 4; r++) sc[f][r] += pen;
            } else if (typ == 4) {
                float mk = blocked[((size_t)b * NB + kb) * BLK + keyl];
                for (int r = 0; r < 4; r++) sc[f][r] += (1.f - mqv[r] * mk) * PENV;
            } else {
                int t = typ - 1;
                const float* bp = band + (((size_t)b * (NB - 4) + (l - 2)) * BLK) * 192;
                for (int r = 0; r < 4; r++) {
                    float bm = bp[(size_t)(sub * 16 + quad * 4 + r) * 192 + t * 64 + keyl];
                    sc[f][r] += (1.f - bm) * PENV;
                }
            }
        }

        // online softmax (16-lane row groups)
        for (int r = 0; r < 4; r++) {
            float mx = fmaxf(fmaxf(sc[0][r], sc[1][r]), fmaxf(sc[2][r], sc[3][r]));
            for (int off = 1; off < 16; off <<= 1)
                mx = fmaxf(mx, __shfl_xor(mx, off, 64));
            float mnew = fmaxf(mrun[r], mx);
            float scale = __expf(mrun[r] - mnew);
            float rs = 0.f;
            for (int f = 0; f < 4; f++) {
                float p = __expf(sc[f][r] - mnew);
                sc[f][r] = p;
                rs += p;
            }
            for (int off = 1; off < 16; off <<= 1)
                rs += __shfl_xor(rs, off, 64);
            lrun[r] = lrun[r] * scale + rs;
            mrun[r] = mnew;
            for (int j = 0; j < 4; j++) ctx[j][r] *= scale;
        }

        // P: C-layout -> wave-private LDS -> A-layout (no barrier needed)
        for (int f = 0; f < 4; f++)
            for (int r = 0; r < 4; r++)
                pw[(quad * 4 + r) * 72 + f * 16 + lm] = (bf16)sc[f][r];
        bf16x8 ap0 = *reinterpret_cast<const bf16x8*>(pw + lm * 72 + quad * 8);
        bf16x8 ap1 = *reinterpret_cast<const bf16x8*>(pw + lm * 72 + 32 + quad * 8);

        // PV: B-frags direct from global (V stored d-major)
        const bf16* vtb = vt + (size_t)bh * HD * SEQ + (size_t)kb * BLK;
        for (int j = 0; j < 4; j++) {
            bf16x8 bv0 = *reinterpret_cast<const bf16x8*>(vtb + (size_t)(j * 16 + lm) * SEQ + quad * 8);
            bf16x8 bv1 = *reinterpret_cast<const bf16x8*>(vtb + (size_t)(j * 16 + lm) * SEQ + 32 + quad * 8);
            ctx[j] = mfma16(ap0, bv0, ctx[j]);
            ctx[j] = mfma16(ap1, bv1, ctx[j]);
        }
    }

    if (!fullmode) {
        // independent waves: finalize and store
        for (int r = 0; r < 4; r++) {
            int sq = l * BLK + sub * 16 + quad * 4 + r;
            float fm = fromm[(size_t)b * SEQ + sq];
            float inv = 1.f / lrun[r];
            for (int j = 0; j < 4; j++)
                attn[((size_t)(b * SEQ + sq)) * HID + h * HD + j * 16 + lm] =
                    (bf16)(ctx[j][r] * inv * fm);
        }
    } else {
        // cross-wave online-softmax combine (4 partials over the same 16 rows)
        float* ctxL = (float*)smem;                    // [4][16][64]
        float* mL   = (float*)(smem + 16384);          // [4][16]
        float* lL   = (float*)(smem + 16384 + 256);    // [4][16]
        __syncthreads();   // all waves done with pw (overlaps ctxL)
        for (int j = 0; j < 4; j++)
            for (int r = 0; r < 4; r++)
                ctxL[wave * 1024 + (quad * 4 + r) * 64 + j * 16 + lm] = ctx[j][r];
        if (lm == 0)
            for (int r = 0; r < 4; r++) {
                mL[wave * 16 + quad * 4 + r] = mrun[r];
                lL[wave * 16 + quad * 4 + r] = lrun[r];
            }
        __syncthreads();
        int row = tid >> 4, c0 = (tid & 15) * 4;
        float M = -1e30f;
        for (int w = 0; w < 4; w++) M = fmaxf(M, mL[w * 16 + row]);
        float Lt = 0.f, a0 = 0.f, a1 = 0.f, a2 = 0.f, a3 = 0.f;
        for (int w = 0; w < 4; w++) {
            float e = __expf(mL[w * 16 + row] - M);
            Lt += lL[w * 16 + row] * e;
            a0 += ctxL[w * 1024 + row * 64 + c0 + 0] * e;
            a1 += ctxL[w * 1024 + row * 64 + c0 + 1] * e;
            a2 += ctxL[w * 1024 + row * 64 + c0 + 2] * e;
            a3 += ctxL[w * 1024 + row * 64 + c0 + 3] * e;
        }
        int sq = l * BLK + sub * 16 + row;
        float fm = fromm[(size_t)b * SEQ + sq];
        float inv = 1.f / Lt;
        bf16* dst = attn + ((size_t)(b * SEQ + sq)) * HID + h * HD + c0;
        dst[0] = (bf16)(a0 * inv * fm);
        dst[1] = (bf16)(a1 * inv * fm);
        dst[2] = (bf16)(a2 * inv * fm);
        dst[3] = (bf16)(a3 * inv * fm);
    }
}

// ---------------- GEMM2: output projection ----------------
__global__ __launch_bounds__(256) void gemm_out(const bf16* __restrict__ A,
                                                const bf16* __restrict__ WoT,
                                                const float* __restrict__ bo,
                                                float* __restrict__ out) {
    __shared__ __align__(16) bf16 As[128 * 64];
    __shared__ __align__(16) bf16 Bs[128 * 64];
    int tid = threadIdx.x;
    int wave = tid >> 6, lane = tid & 63;
    int quad = lane >> 4, lm = lane & 15;
    int tile_m = blockIdx.x * 128;
    int tile_n = blockIdx.y * 128;
    int wm = (wave & 1) * 64, wn = (wave >> 1) * 64;

    floatx4 acc[4][4] = {};

    for (int k0 = 0; k0 < HID; k0 += 64) {
        __syncthreads();
        for (int it = 0; it < 4; it++) {
            int c = it * 256 + tid;
            int row = c >> 3, col = (c & 7) * 8;
            async_ld16(A + (size_t)(tile_m + row) * HID + k0 + col, &As[c * 8]);
            async_ld16(WoT + (size_t)(tile_n + row) * HID + k0 + col, &Bs[c * 8]);
        }
        __syncthreads();
        for (int ks = 0; ks < 64; ks += 32) {
            bf16x8 a[4], b[4];
            for (int i = 0; i < 4; i++)
                a[i] = *reinterpret_cast<const bf16x8*>(&As[(wm + i * 16 + lm) * 64 + ks + quad * 8]);
            for (int j = 0; j < 4; j++)
                b[j] = *reinterpret_cast<const bf16x8*>(&Bs[(wn + j * 16 + lm) * 64 + ks + quad * 8]);
            for (int i = 0; i < 4; i++)
                for (int j = 0; j < 4; j++)
                    acc[i][j] = mfma16(a[i], b[j], acc[i][j]);
        }
    }

    for (int i = 0; i < 4; i++) {
        for (int j = 0; j < 4; j++) {
            int nn = tile_n + wn + j * 16 + lm;
            float bsv = bo[nn];
            for (int r = 0; r < 4; r++) {
                int mm = tile_m + wm + i * 16 + quad * 4 + r;
                int b_ = mm >> 12, s = mm & 4095;
                if (s < LQ)
                    out[((size_t)(b_ * LQ + s)) * HID + nn] = acc[i][j][r] + bsv;
            }
        }
    }
}

// ---------------- launcher ----------------
extern "C" void kernel_launch(void* const* d_in, const int* in_sizes, int n_in,
                              void* d_out, int out_size, void* d_ws, size_t ws_size,
                              hipStream_t stream) {
    const float* X       = (const float*)d_in[0];
    const float* Wq      = (const float*)d_in[1];
    const float* bq      = (const float*)d_in[2];
    const float* Wk      = (const float*)d_in[3];
    const float* bk      = (const float*)d_in[4];
    const float* Wv      = (const float*)d_in[5];
    const float* bv      = (const float*)d_in[6];
    const float* Wo      = (const float*)d_in[7];
    const float* bo      = (const float*)d_in[8];
    const float* band    = (const float*)d_in[9];
    const float* fromm   = (const float*)d_in[10];
    const float* tom     = (const float*)d_in[11];
    const float* blocked = (const float*)d_in[12];
    const int*   randa   = (const int*)d_in[13];
    float* out = (float*)d_out;

    char* ws = (char*)d_ws;
    bf16* Xp    = (bf16*)(ws + 0);              // 16,777,216 B (reused as attn)
    bf16* WqkvT = (bf16*)(ws + 16777216);       //  6,291,456 B
    bf16* WoT   = (bf16*)(ws + 23068672);       //  2,097,152 B
    bf16* qb    = (bf16*)(ws + 25165824);       // 16,777,216 B
    bf16* kb    = (bf16*)(ws + 41943040);       // 16,777,216 B
    bf16* vtb   = (bf16*)(ws + 58720256);       // 16,777,216 B (d-major V)
    bf16* attnb = Xp;                           // Xp dead after gemm_qkv

    cast_pad_x<<<dim3(8192), dim3(256), 0, stream>>>(X, Xp);
    transpose_w<<<dim3(16, 16, 4), dim3(64, 4), 0, stream>>>(Wq, Wk, Wv, Wo, WqkvT, WoT);
    gemm_qkv<<<dim3(64, 24), dim3(256), 0, stream>>>(Xp, WqkvT, bq, bk, bv, qb, kb, vtb);
    attn_kernel<<<dim3(70, BB * NH), dim3(256), 0, stream>>>(qb, kb, vtb, band, fromm, tom,
                                                             blocked, randa, attnb);
    gemm_out<<<dim3(64, 8), dim3(256), 0, stream>>>(attnb, WoT, bo, out);
}